// Round 1
// baseline (1132.854 us; speedup 1.0000x reference)
//
#include <hip/hip_runtime.h>
#include <cstdint>
#include <cstddef>

// Problem constants
#define NBS  512
#define NEN  512
#define NSEQ 64
#define DENT 256
#define DIN  1024
#define DKEY 32
#define DF   256
// H = 32, 4H = 128

// ---------------------------------------------------------------------------
// Generic tiled f32 GEMM: out = op(A[M,K] @ W[K,N] + bias) (+ optional addvec)
// KEYMODE remaps output rows (row = b*512+n) into key layout [b][513][32].
// ---------------------------------------------------------------------------
template<int BM, int BN, int BK, int TM, int TN, bool RELU, bool ADDVEC, bool KEYMODE>
__global__ __launch_bounds__((BM/TM)*(BN/TN))
void gemm_tile(const float* __restrict__ A, int lda,
               const float* __restrict__ W, int ldw,
               const float* __restrict__ bias,
               const float* __restrict__ addvec, int ldadd,
               float* __restrict__ out, int ldo,
               int K, int out_row_offset)
{
    constexpr int TCOLS = BN / TN;
    constexpr int TROWS = BM / TM;
    constexpr int NT = TCOLS * TROWS;
    __shared__ float As[BK][BM + 4];   // transposed A tile
    __shared__ float Ws[BK][BN + 4];
    const int tid  = threadIdx.x;
    const int row0 = blockIdx.x * BM;
    const int n0   = blockIdx.y * BN;
    const int tx   = tid % TCOLS;
    const int ty   = tid / TCOLS;

    float acc[TM][TN];
#pragma unroll
    for (int u = 0; u < TM; u++)
#pragma unroll
        for (int v = 0; v < TN; v++) acc[u][v] = 0.f;

    for (int k0 = 0; k0 < K; k0 += BK) {
        constexpr int KQ  = BK / 4;       // float4 groups along K per row
        constexpr int RPP = NT / KQ;      // rows loaded per pass
#pragma unroll
        for (int r = 0; r < BM; r += RPP) {
            int rr = r + tid / KQ;
            int kk = (tid % KQ) * 4;
            float4 a4 = *(const float4*)(A + (size_t)(row0 + rr) * lda + k0 + kk);
            As[kk + 0][rr] = a4.x; As[kk + 1][rr] = a4.y;
            As[kk + 2][rr] = a4.z; As[kk + 3][rr] = a4.w;
        }
        constexpr int NQ = BN / 4;
        constexpr int KR = NT / NQ;
#pragma unroll
        for (int kk = 0; kk < BK; kk += KR) {
            int kr = kk + tid / NQ;
            int nn = (tid % NQ) * 4;
            *(float4*)(&Ws[kr][nn]) = *(const float4*)(W + (size_t)(k0 + kr) * ldw + n0 + nn);
        }
        __syncthreads();
#pragma unroll
        for (int k = 0; k < BK; k++) {
            float av[TM], wv[TN];
#pragma unroll
            for (int u = 0; u < TM; u += 4) {
                float4 t = *(const float4*)(&As[k][ty * TM + u]);
                av[u] = t.x; av[u + 1] = t.y; av[u + 2] = t.z; av[u + 3] = t.w;
            }
#pragma unroll
            for (int v = 0; v < TN; v += 4) {
                float4 t = *(const float4*)(&Ws[k][tx * TN + v]);
                wv[v] = t.x; wv[v + 1] = t.y; wv[v + 2] = t.z; wv[v + 3] = t.w;
            }
#pragma unroll
            for (int u = 0; u < TM; u++)
#pragma unroll
                for (int v = 0; v < TN; v++) acc[u][v] += av[u] * wv[v];
        }
        __syncthreads();
    }

#pragma unroll
    for (int u = 0; u < TM; u++) {
        int row = row0 + ty * TM + u;
        int b_  = row & 511;
        size_t obase;
        if (KEYMODE) obase = ((size_t)(row >> 9) * 513 + b_) * 32;
        else         obase = (size_t)(row + out_row_offset) * ldo;
#pragma unroll
        for (int v = 0; v < TN; v += 4) {
            int col = n0 + tx * TN + v;
            float vals[4];
#pragma unroll
            for (int j = 0; j < 4; j++) {
                float val = acc[u][v + j] + bias[col + j];
                if (RELU) val = fmaxf(val, 0.f);
                vals[j] = val;
            }
            if (ADDVEC) {
                float4 a4 = *(const float4*)(addvec + (size_t)b_ * ldadd + col);
                vals[0] += a4.x; vals[1] += a4.y; vals[2] += a4.z; vals[3] += a4.w;
            }
            float4 r4; r4.x = vals[0]; r4.y = vals[1]; r4.z = vals[2]; r4.w = vals[3];
            *(float4*)(out + obase + col) = r4;
        }
    }
}

// ---------------------------------------------------------------------------
// key fixup: zero pad row 512, scatter end_embedding at row entity_num[b]
// ---------------------------------------------------------------------------
__global__ void key_fixup(const int* __restrict__ en, const float* __restrict__ eemb,
                          float* __restrict__ key)
{
    int b = blockIdx.x;
    int t = threadIdx.x;   // 32
    key[((size_t)b * 513 + 512) * 32 + t] = 0.f;
    key[((size_t)b * 513 + en[b]) * 32 + t] = eemb[t];
}

// ---------------------------------------------------------------------------
// prep: per batch b — first-occurrence index fs[b][n], end step T, and the
// per-step mean-pooled embedding EMB[i*512+b][0:32]
// ---------------------------------------------------------------------------
__global__ __launch_bounds__(64) void prep_kernel(
    const int* __restrict__ en_g, const int* __restrict__ su_g,
    const int* __restrict__ sun_g, const float* __restrict__ key,
    int* __restrict__ fs_g, float* __restrict__ EMB)
{
    int b = blockIdx.x;
    int tid = threadIdx.x;   // 64
    __shared__ int fs_l[513];
    __shared__ int su_l[64];
    for (int i = tid; i < 513; i += 64) fs_l[i] = 64;
    su_l[tid] = su_g[b * 64 + tid];
    __syncthreads();
    atomicMin(&fs_l[su_l[tid]], tid);
    int en = en_g[b];
    unsigned long long ball = __ballot(su_l[tid] == en);
    int T = ball ? (__ffsll(ball) - 1) : 64;
    __syncthreads();
    for (int i = tid; i < 513; i += 64) fs_g[(size_t)b * 513 + i] = fs_l[i];

    int sun = sun_g[b];
    float a = 0.f;
    int cnt = 0;
    for (int i = 0; i < 64; i++) {
        int su_i = su_l[i];
        bool nw = (i < T) && (fs_l[su_i] == i);
        if (nw) {
            cnt++;
            if (tid < 32) a += key[((size_t)b * 513 + su_i) * 32 + tid];
        }
        float denom = (sun != 0 && cnt > 0) ? (float)cnt : 1.0f;
        if (tid < 32) EMB[((size_t)i * 512 + b) * 32 + tid] = a / denom;
    }
}

// ---------------------------------------------------------------------------
// AE rows 0..511 = autoregressive_embedding
// ---------------------------------------------------------------------------
__global__ void ae_init(const float* __restrict__ ar, float* __restrict__ AE)
{
    int i = (blockIdx.x * blockDim.x + threadIdx.x) * 4;
    *(float4*)(AE + i) = *(const float4*)(ar + i);
}

// ---------------------------------------------------------------------------
// LN-LSTM: one block per batch, 128 threads (one per gate dim), 64 steps.
// ---------------------------------------------------------------------------
__device__ inline float wave_sum64(float v)
{
#pragma unroll
    for (int m = 1; m <= 32; m <<= 1) v += __shfl_xor(v, m, 64);
    return v;
}
__device__ inline float sigm(float x) { return 1.0f / (1.0f + expf(-x)); }

__global__ __launch_bounds__(128) void lstm_kernel(
    const float* __restrict__ X, const float* __restrict__ wih_g,
    const float* __restrict__ whh_g,
    const float* __restrict__ lnig, const float* __restrict__ lnib,
    const float* __restrict__ lnhg, const float* __restrict__ lnhb,
    const float* __restrict__ lncg, const float* __restrict__ lncb,
    float* __restrict__ Q)
{
    int b = blockIdx.x;
    int tid = threadIdx.x;          // 0..127
    int lane = tid & 63, wv = tid >> 6;
    __shared__ float wih[32 * 128], whh[32 * 128];
    for (int i = tid; i < 4096; i += 128) { wih[i] = wih_g[i]; whh[i] = whh_g[i]; }
    __shared__ float xv[32], hv[32], cv[32], gl[128], red[8];
    if (tid < 32) { hv[tid] = 0.f; cv[tid] = 0.f; }
    float gi = lnig[tid], bi = lnib[tid], gh = lnhg[tid], bh = lnhb[tid];
    float gc = 0.f, bc = 0.f;
    if (tid < 32) { gc = lncg[tid]; bc = lncb[tid]; }
    __syncthreads();

    for (int s = 0; s < 64; s++) {
        if (tid < 32) xv[tid] = X[((size_t)s * 512 + b) * 32 + tid];
        __syncthreads();
        float ax = 0.f, ah = 0.f;
#pragma unroll
        for (int k = 0; k < 32; k++) {
            ax += xv[k] * wih[k * 128 + tid];
            ah += hv[k] * whh[k * 128 + tid];
        }
        float s0 = wave_sum64(ax), s1 = wave_sum64(ax * ax);
        float s2 = wave_sum64(ah), s3 = wave_sum64(ah * ah);
        if (lane == 0) { red[wv*4+0]=s0; red[wv*4+1]=s1; red[wv*4+2]=s2; red[wv*4+3]=s3; }
        __syncthreads();
        float mx = (red[0] + red[4]) * (1.f/128.f);
        float vx = (red[1] + red[5]) * (1.f/128.f) - mx * mx;
        float mh = (red[2] + red[6]) * (1.f/128.f);
        float vh = (red[3] + red[7]) * (1.f/128.f) - mh * mh;
        float gate = (ax - mx) * rsqrtf(vx + 1e-5f) * gi + bi
                   + (ah - mh) * rsqrtf(vh + 1e-5f) * gh + bh;
        gl[tid] = gate;
        __syncthreads();
        if (tid < 32) {
            float igv = gl[tid], fgv = gl[32 + tid], cgv = gl[64 + tid], ogv = gl[96 + tid];
            float cc = sigm(fgv) * cv[tid] + sigm(igv) * tanhf(cgv);
            float u0 = cc, u1 = cc * cc;
#pragma unroll
            for (int m = 1; m <= 16; m <<= 1) {
                u0 += __shfl_xor(u0, m, 32);
                u1 += __shfl_xor(u1, m, 32);
            }
            float mc = u0 * (1.f/32.f);
            float vc = u1 * (1.f/32.f) - mc * mc;
            float cn = (cc - mc) * rsqrtf(vc + 1e-5f) * gc + bc;
            float hn = sigm(ogv) * tanhf(cn);
            cv[tid] = cn; hv[tid] = hn;
            Q[((size_t)b * 64 + s) * 32 + tid] = hn;
        }
        __syncthreads();
    }
}

// ---------------------------------------------------------------------------
// logits: out[b][s][n] = mask ? dot(Q[b][s], key[b][n]) : -1e9
// mask_s[n] = (s==0) ? n<en : (n<=en && first_sel>=s)
// ---------------------------------------------------------------------------
__global__ __launch_bounds__(128) void logits_kernel(
    const float* __restrict__ key, const float* __restrict__ Q,
    const int* __restrict__ fs_g, const int* __restrict__ en_g,
    float* __restrict__ out)
{
    int b = blockIdx.x;
    int n0 = blockIdx.y * 128;
    int tid = threadIdx.x;
    __shared__ float Qs[64 * 32];
    __shared__ float Ks[128 * 33];
    for (int i = tid * 4; i < 2048; i += 512)
        *(float4*)(&Qs[i]) = *(const float4*)(Q + (size_t)b * 2048 + i);
    for (int i = tid; i < 4096; i += 128) {
        int r = i >> 5, d = i & 31;
        int n = n0 + r;
        Ks[r * 33 + d] = (n < 513) ? key[((size_t)b * 513 + n) * 32 + d] : 0.f;
    }
    __syncthreads();
    int n = n0 + tid;
    if (n < 513) {
        int en = en_g[b];
        int f = fs_g[(size_t)b * 513 + n];
        float kreg[32];
#pragma unroll
        for (int d = 0; d < 32; d++) kreg[d] = Ks[tid * 33 + d];
        for (int s = 0; s < 64; s++) {
            float a = 0.f;
#pragma unroll
            for (int d = 0; d < 32; d++) a += Qs[s * 32 + d] * kreg[d];
            bool m = (s == 0) ? (n < en) : ((n <= en) && (f >= s));
            out[((size_t)b * 64 + s) * 513 + n] = m ? a : -1e9f;
        }
    }
}

// ---------------------------------------------------------------------------
extern "C" void kernel_launch(void* const* d_in, const int* in_sizes, int n_in,
                              void* d_out, int out_size, void* d_ws, size_t ws_size,
                              hipStream_t stream)
{
    const float* ee   = (const float*)d_in[0];
    const float* ar   = (const float*)d_in[1];
    const int*   en   = (const int*)d_in[2];
    const int*   su   = (const int*)d_in[3];
    const int*   sun  = (const int*)d_in[4];
    const float* kw   = (const float*)d_in[5];
    const float* kb   = (const float*)d_in[6];
    const float* q1w  = (const float*)d_in[7];
    const float* q1b  = (const float*)d_in[8];
    const float* q2w  = (const float*)d_in[9];
    const float* q2b  = (const float*)d_in[10];
    const float* e1w  = (const float*)d_in[11];
    const float* e1b  = (const float*)d_in[12];
    const float* e2w  = (const float*)d_in[13];
    const float* e2b  = (const float*)d_in[14];
    const float* eemb = (const float*)d_in[15];
    const float* wih  = (const float*)d_in[16];
    const float* whh  = (const float*)d_in[17];
    const float* lnig = (const float*)d_in[18];
    const float* lnib = (const float*)d_in[19];
    const float* lnhg = (const float*)d_in[20];
    const float* lnhb = (const float*)d_in[21];
    const float* lncg = (const float*)d_in[22];
    const float* lncb = (const float*)d_in[23];
    float* outp = (float*)d_out;

    float* ws = (float*)d_ws;
    float* key = ws;  ws += (size_t)512 * 513 * 32;       // 8,404,992
    float* AE  = ws;  ws += (size_t)64 * 512 * 1024;      // 33,554,432
    float* Z1  = ws;  ws += (size_t)64 * 512 * 256;       // 8,388,608 (also Y1)
    float* EMB = ws;  ws += (size_t)64 * 512 * 32;        // 1,048,576
    float* X   = ws;  ws += (size_t)64 * 512 * 32;        // 1,048,576
    float* Q   = ws;  ws += (size_t)512 * 64 * 32;        // 1,048,576
    int*   fs  = (int*)ws;                                // 262,656 ints
    // total ~215 MB

    // 1. key = ee @ key_fc_w + b  (M=262144, N=32, K=256) -> key layout [b][513][32]
    gemm_tile<128, 32, 16, 8, 4, false, false, true><<<dim3(2048, 1), 128, 0, stream>>>(
        ee, 256, kw, 32, kb, nullptr, 0, key, 32, 256, 0);
    key_fixup<<<512, 32, 0, stream>>>(en, eemb, key);
    prep_kernel<<<512, 64, 0, stream>>>(en, su, sun, key, fs, EMB);

    // 2. Z1 = relu(EMB @ e1_w + e1_b)   (M=32256, N=256, K=32)
    gemm_tile<128, 128, 16, 8, 8, true, false, false><<<dim3(252, 2), 256, 0, stream>>>(
        EMB, 32, e1w, 256, e1b, nullptr, 0, Z1, 256, 32, 0);
    ae_init<<<512, 256, 0, stream>>>(ar, AE);
    // 3. AE[512..] = ar + Z1 @ e2_w + e2_b  (M=32256, N=1024, K=256)
    gemm_tile<128, 128, 16, 8, 8, false, true, false><<<dim3(252, 8), 256, 0, stream>>>(
        Z1, 256, e2w, 1024, e2b, ar, 1024, AE, 1024, 256, 512);
    // 4. Y1 = relu(AE @ q1_w + q1_b)  (M=32768, N=256, K=1024) -> reuse Z1
    gemm_tile<128, 128, 16, 8, 8, true, false, false><<<dim3(256, 2), 256, 0, stream>>>(
        AE, 1024, q1w, 256, q1b, nullptr, 0, Z1, 256, 1024, 0);
    // 5. X = Y1 @ q2_w + q2_b  (M=32768, N=32, K=256)
    gemm_tile<128, 32, 16, 8, 4, false, false, false><<<dim3(256, 1), 128, 0, stream>>>(
        Z1, 256, q2w, 32, q2b, nullptr, 0, X, 32, 256, 0);

    // 6. LN-LSTM over 64 steps -> queries
    lstm_kernel<<<512, 128, 0, stream>>>(X, wih, whh, lnig, lnib, lnhg, lnhb, lncg, lncb, Q);

    // 7. logits + mask
    logits_kernel<<<dim3(512, 5), 128, 0, stream>>>(key, Q, fs, en, outp);
}

// Round 2
// 767.165 us; speedup vs baseline: 1.4767x; 1.4767x over previous
//
#include <hip/hip_runtime.h>
#include <cstdint>
#include <cstddef>

// Problem constants: BS=512, EN=512, SEQ=64, D_ENT=256, D_IN=1024, D_KEY=32, D_F=256, H=32

typedef short bf16x8 __attribute__((ext_vector_type(8)));
typedef float f32x4  __attribute__((ext_vector_type(4)));

__device__ __forceinline__ ushort f2bf(float f) {
    union { float f; unsigned u; } x; x.f = f;
    unsigned r = x.u + 0x7fffu + ((x.u >> 16) & 1u);   // round-to-nearest-even
    return (ushort)(r >> 16);
}

__device__ __forceinline__ void gld16(const void* g, void* l) {
    __builtin_amdgcn_global_load_lds(
        (const __attribute__((address_space(1))) void*)g,
        (__attribute__((address_space(3))) void*)l,
        16, 0, 0);
}

// ---------------------------------------------------------------------------
// bf16 MFMA GEMM: out = op(A[M,K] @ B[K,N] + bias [+ addvec]).
// B supplied pre-transposed as BT[N,K] bf16 so both fragments are contiguous
// ds_read_b128. A is bf16 (global_load_lds) or fp32 (load+cvt staging).
// KEYMODE remaps out row r=b*512+n into key layout [b][513][32].
// ---------------------------------------------------------------------------
template<int BM, int BN, int BK, int WR, int WC,
         bool RELU, bool ADDVEC, bool OUT_BF16, bool A_F32, bool KEYMODE>
__global__ __launch_bounds__(WR * WC * 64)
void mfma_gemm(const void* __restrict__ Av, int lda,
               const ushort* __restrict__ BT,
               const float* __restrict__ bias,
               const float* __restrict__ addvec, int ldadd,
               void* __restrict__ outv, int ldo,
               int K, int out_row_offset)
{
    constexpr int NT  = WR * WC * 64;
    constexpr int WM  = BM / WR, WN = BN / WC;
    constexpr int TMt = WM / 16, TNt = WN / 16;
    constexpr int KC  = BK / 8;          // 16B chunks per row
    constexpr int CHA = BM * KC, CHB = BN * KC;
    __shared__ __align__(16) ushort As[BM * BK];
    __shared__ __align__(16) ushort Bs[BN * BK];

    const int tid  = threadIdx.x;
    const int lane = tid & 63;
    const int w    = tid >> 6;
    const int wr   = w / WC, wc = w % WC;
    const int row0 = blockIdx.x * BM;
    const int n0   = blockIdx.y * BN;

    f32x4 acc[TMt][TNt];
#pragma unroll
    for (int i = 0; i < TMt; i++)
#pragma unroll
        for (int j = 0; j < TNt; j++)
#pragma unroll
            for (int r = 0; r < 4; r++) acc[i][j][r] = 0.f;

    const ushort* Ab = (const ushort*)Av;
    const float*  Af = (const float*)Av;

    for (int k0 = 0; k0 < K; k0 += BK) {
        if (A_F32) {
#pragma unroll
            for (int id = tid; id < CHA; id += NT) {
                int r = id / KC, kc = id % KC;
                const float* src = Af + (size_t)(row0 + r) * lda + k0 + kc * 8;
                float4 v0 = *(const float4*)(src);
                float4 v1 = *(const float4*)(src + 4);
                bf16x8 p;
                p[0] = (short)f2bf(v0.x); p[1] = (short)f2bf(v0.y);
                p[2] = (short)f2bf(v0.z); p[3] = (short)f2bf(v0.w);
                p[4] = (short)f2bf(v1.x); p[5] = (short)f2bf(v1.y);
                p[6] = (short)f2bf(v1.z); p[7] = (short)f2bf(v1.w);
                *(bf16x8*)(&As[id * 8]) = p;
            }
        } else {
#pragma unroll
            for (int id = tid; id < CHA; id += NT) {
                int r = id / KC, kc = id % KC;
                gld16(Ab + (size_t)(row0 + r) * lda + k0 + kc * 8, &As[id * 8]);
            }
        }
#pragma unroll
        for (int id = tid; id < CHB; id += NT) {
            int r = id / KC, kc = id % KC;
            gld16(BT + (size_t)(n0 + r) * K + k0 + kc * 8, &Bs[id * 8]);
        }
        __syncthreads();

        bf16x8 afr[TMt], bfr[TNt];
        const int krd = (lane >> 4) * 8;
        const int mrd = lane & 15;
#pragma unroll
        for (int tm = 0; tm < TMt; tm++)
            afr[tm] = *(bf16x8*)(&As[(wr * WM + tm * 16 + mrd) * BK + krd]);
#pragma unroll
        for (int tn = 0; tn < TNt; tn++)
            bfr[tn] = *(bf16x8*)(&Bs[(wc * WN + tn * 16 + mrd) * BK + krd]);
#pragma unroll
        for (int tm = 0; tm < TMt; tm++)
#pragma unroll
            for (int tn = 0; tn < TNt; tn++)
                acc[tm][tn] = __builtin_amdgcn_mfma_f32_16x16x32_bf16(
                    afr[tm], bfr[tn], acc[tm][tn], 0, 0, 0);
        __syncthreads();
    }

    // Epilogue. C layout: col = lane&15, row = (lane>>4)*4 + reg
    float*  outf = (float*)outv;
    ushort* outh = (ushort*)outv;
    const int cn = lane & 15;
    const int rb = (lane >> 4) * 4;
#pragma unroll
    for (int tm = 0; tm < TMt; tm++) {
#pragma unroll
        for (int r = 0; r < 4; r++) {
            int grow = row0 + wr * WM + tm * 16 + rb + r;
            int b_   = grow & 511;
#pragma unroll
            for (int tn = 0; tn < TNt; tn++) {
                int gcol = n0 + wc * WN + tn * 16 + cn;
                float v = acc[tm][tn][r] + bias[gcol];
                if (RELU)   v = fmaxf(v, 0.f);
                if (ADDVEC) v += addvec[(size_t)b_ * ldadd + gcol];
                size_t oidx;
                if (KEYMODE) oidx = ((size_t)(grow >> 9) * 513 + b_) * 32 + gcol;
                else         oidx = (size_t)(grow + out_row_offset) * ldo + gcol;
                if (OUT_BF16) outh[oidx] = f2bf(v);
                else          outf[oidx] = v;
            }
        }
    }
}

// ---------------------------------------------------------------------------
// Weight transpose + fp32->bf16: WT[n*K+k] = W[k*N+n].  K,N multiples of 32.
// ---------------------------------------------------------------------------
__global__ __launch_bounds__(256) void wt_cvt(const float* __restrict__ W,
                                              ushort* __restrict__ WT, int K, int N)
{
    __shared__ float t[32][33];
    int kt = blockIdx.x * 32, nt = blockIdx.y * 32;
    int x = threadIdx.x & 31, y = threadIdx.x >> 5;   // 32 x 8
    for (int i = y; i < 32; i += 8) t[i][x] = W[(size_t)(kt + i) * N + nt + x];
    __syncthreads();
    for (int i = y; i < 32; i += 8) WT[(size_t)(nt + i) * K + kt + x] = f2bf(t[x][i]);
}

// ---------------------------------------------------------------------------
__global__ void key_fixup(const int* __restrict__ en, const float* __restrict__ eemb,
                          float* __restrict__ key)
{
    int b = blockIdx.x;
    int t = threadIdx.x;   // 32
    key[((size_t)b * 513 + 512) * 32 + t] = 0.f;
    key[((size_t)b * 513 + en[b]) * 32 + t] = eemb[t];
}

// ---------------------------------------------------------------------------
// prep: first-occurrence fs[b][n], end step T, per-step pooled EMB (bf16)
// ---------------------------------------------------------------------------
__global__ __launch_bounds__(64) void prep_kernel(
    const int* __restrict__ en_g, const int* __restrict__ su_g,
    const int* __restrict__ sun_g, const float* __restrict__ key,
    int* __restrict__ fs_g, ushort* __restrict__ EMB)
{
    int b = blockIdx.x;
    int tid = threadIdx.x;   // 64
    __shared__ int fs_l[513];
    __shared__ int su_l[64];
    for (int i = tid; i < 513; i += 64) fs_l[i] = 64;
    su_l[tid] = su_g[b * 64 + tid];
    __syncthreads();
    atomicMin(&fs_l[su_l[tid]], tid);
    int en = en_g[b];
    unsigned long long ball = __ballot(su_l[tid] == en);
    int T = ball ? (__ffsll(ball) - 1) : 64;
    __syncthreads();
    for (int i = tid; i < 513; i += 64) fs_g[(size_t)b * 513 + i] = fs_l[i];

    int sun = sun_g[b];
    float a = 0.f;
    int cnt = 0;
    for (int i = 0; i < 64; i++) {
        int su_i = su_l[i];
        bool nw = (i < T) && (fs_l[su_i] == i);
        if (nw) {
            cnt++;
            if (tid < 32) a += key[((size_t)b * 513 + su_i) * 32 + tid];
        }
        float denom = (sun != 0 && cnt > 0) ? (float)cnt : 1.0f;
        if (tid < 32) EMB[((size_t)i * 512 + b) * 32 + tid] = f2bf(a / denom);
    }
}

// ---------------------------------------------------------------------------
__global__ void ae_init(const float* __restrict__ ar, ushort* __restrict__ AEb)
{
    int i = (blockIdx.x * blockDim.x + threadIdx.x) * 4;
    float4 v = *(const float4*)(ar + i);
    ushort4 o;
    o.x = f2bf(v.x); o.y = f2bf(v.y); o.z = f2bf(v.z); o.w = f2bf(v.w);
    *(ushort4*)(AEb + i) = o;
}

// ---------------------------------------------------------------------------
// LN-LSTM: one block per batch, 128 threads (one per gate dim), 64 steps.
// ---------------------------------------------------------------------------
__device__ inline float wave_sum64(float v)
{
#pragma unroll
    for (int m = 1; m <= 32; m <<= 1) v += __shfl_xor(v, m, 64);
    return v;
}
__device__ inline float sigm(float x) { return 1.0f / (1.0f + expf(-x)); }

__global__ __launch_bounds__(128) void lstm_kernel(
    const float* __restrict__ X, const float* __restrict__ wih_g,
    const float* __restrict__ whh_g,
    const float* __restrict__ lnig, const float* __restrict__ lnib,
    const float* __restrict__ lnhg, const float* __restrict__ lnhb,
    const float* __restrict__ lncg, const float* __restrict__ lncb,
    float* __restrict__ Q)
{
    int b = blockIdx.x;
    int tid = threadIdx.x;          // 0..127
    int lane = tid & 63, wv = tid >> 6;
    __shared__ float wih[32 * 128], whh[32 * 128];
    for (int i = tid; i < 4096; i += 128) { wih[i] = wih_g[i]; whh[i] = whh_g[i]; }
    __shared__ float xv[32], hv[32], cv[32], gl[128], red[8];
    if (tid < 32) { hv[tid] = 0.f; cv[tid] = 0.f; }
    float gi = lnig[tid], bi = lnib[tid], gh = lnhg[tid], bh = lnhb[tid];
    float gc = 0.f, bc = 0.f;
    if (tid < 32) { gc = lncg[tid]; bc = lncb[tid]; }
    __syncthreads();

    for (int s = 0; s < 64; s++) {
        if (tid < 32) xv[tid] = X[((size_t)s * 512 + b) * 32 + tid];
        __syncthreads();
        float ax = 0.f, ah = 0.f;
#pragma unroll
        for (int k = 0; k < 32; k++) {
            ax += xv[k] * wih[k * 128 + tid];
            ah += hv[k] * whh[k * 128 + tid];
        }
        float s0 = wave_sum64(ax), s1 = wave_sum64(ax * ax);
        float s2 = wave_sum64(ah), s3 = wave_sum64(ah * ah);
        if (lane == 0) { red[wv*4+0]=s0; red[wv*4+1]=s1; red[wv*4+2]=s2; red[wv*4+3]=s3; }
        __syncthreads();
        float mx = (red[0] + red[4]) * (1.f/128.f);
        float vx = (red[1] + red[5]) * (1.f/128.f) - mx * mx;
        float mh = (red[2] + red[6]) * (1.f/128.f);
        float vh = (red[3] + red[7]) * (1.f/128.f) - mh * mh;
        float gate = (ax - mx) * rsqrtf(vx + 1e-5f) * gi + bi
                   + (ah - mh) * rsqrtf(vh + 1e-5f) * gh + bh;
        gl[tid] = gate;
        __syncthreads();
        if (tid < 32) {
            float igv = gl[tid], fgv = gl[32 + tid], cgv = gl[64 + tid], ogv = gl[96 + tid];
            float cc = sigm(fgv) * cv[tid] + sigm(igv) * tanhf(cgv);
            float u0 = cc, u1 = cc * cc;
#pragma unroll
            for (int m = 1; m <= 16; m <<= 1) {
                u0 += __shfl_xor(u0, m, 32);
                u1 += __shfl_xor(u1, m, 32);
            }
            float mc = u0 * (1.f/32.f);
            float vc = u1 * (1.f/32.f) - mc * mc;
            float cn = (cc - mc) * rsqrtf(vc + 1e-5f) * gc + bc;
            float hn = sigm(ogv) * tanhf(cn);
            cv[tid] = cn; hv[tid] = hn;
            Q[((size_t)b * 64 + s) * 32 + tid] = hn;
        }
        __syncthreads();
    }
}

// ---------------------------------------------------------------------------
// logits: out[b][s][n] = mask ? dot(Q[b][s], key[b][n]) : -1e9
// ---------------------------------------------------------------------------
__global__ __launch_bounds__(128) void logits_kernel(
    const float* __restrict__ key, const float* __restrict__ Q,
    const int* __restrict__ fs_g, const int* __restrict__ en_g,
    float* __restrict__ out)
{
    int b = blockIdx.x;
    int n0 = blockIdx.y * 128;
    int tid = threadIdx.x;
    __shared__ float Qs[64 * 32];
    __shared__ float Ks[128 * 33];
    for (int i = tid * 4; i < 2048; i += 512)
        *(float4*)(&Qs[i]) = *(const float4*)(Q + (size_t)b * 2048 + i);
    for (int i = tid; i < 4096; i += 128) {
        int r = i >> 5, d = i & 31;
        int n = n0 + r;
        Ks[r * 33 + d] = (n < 513) ? key[((size_t)b * 513 + n) * 32 + d] : 0.f;
    }
    __syncthreads();
    int n = n0 + tid;
    if (n < 513) {
        int en = en_g[b];
        int f = fs_g[(size_t)b * 513 + n];
        float kreg[32];
#pragma unroll
        for (int d = 0; d < 32; d++) kreg[d] = Ks[tid * 33 + d];
        for (int s = 0; s < 64; s++) {
            float a = 0.f;
#pragma unroll
            for (int d = 0; d < 32; d++) a += Qs[s * 32 + d] * kreg[d];
            bool m = (s == 0) ? (n < en) : ((n <= en) && (f >= s));
            out[((size_t)b * 64 + s) * 513 + n] = m ? a : -1e9f;
        }
    }
}

// ---------------------------------------------------------------------------
extern "C" void kernel_launch(void* const* d_in, const int* in_sizes, int n_in,
                              void* d_out, int out_size, void* d_ws, size_t ws_size,
                              hipStream_t stream)
{
    const float* ee   = (const float*)d_in[0];
    const float* ar   = (const float*)d_in[1];
    const int*   en   = (const int*)d_in[2];
    const int*   su   = (const int*)d_in[3];
    const int*   sun  = (const int*)d_in[4];
    const float* kw   = (const float*)d_in[5];
    const float* kb   = (const float*)d_in[6];
    const float* q1w  = (const float*)d_in[7];
    const float* q1b  = (const float*)d_in[8];
    const float* q2w  = (const float*)d_in[9];
    const float* q2b  = (const float*)d_in[10];
    const float* e1w  = (const float*)d_in[11];
    const float* e1b  = (const float*)d_in[12];
    const float* e2w  = (const float*)d_in[13];
    const float* e2b  = (const float*)d_in[14];
    const float* eemb = (const float*)d_in[15];
    const float* wih  = (const float*)d_in[16];
    const float* whh  = (const float*)d_in[17];
    const float* lnig = (const float*)d_in[18];
    const float* lnib = (const float*)d_in[19];
    const float* lnhg = (const float*)d_in[20];
    const float* lnhb = (const float*)d_in[21];
    const float* lncg = (const float*)d_in[22];
    const float* lncb = (const float*)d_in[23];
    float* outp = (float*)d_out;

    char* p = (char*)d_ws;
    float*  key  = (float*)p;  p += (size_t)512 * 513 * 32 * 4;   // 33.6 MB
    ushort* AEb  = (ushort*)p; p += (size_t)32768 * 1024 * 2;     // 67 MB
    ushort* Z1b  = (ushort*)p; p += (size_t)32768 * 256 * 2;      // 16.8 MB
    ushort* EMBb = (ushort*)p; p += (size_t)32768 * 32 * 2;       // 2 MB
    float*  X    = (float*)p;  p += (size_t)32768 * 32 * 4;       // 4 MB
    float*  Q    = (float*)p;  p += (size_t)32768 * 32 * 4;       // 4 MB
    int*    fs   = (int*)p;    p += (size_t)512 * 513 * 4;        // 1.05 MB
    ushort* kwt  = (ushort*)p; p += (size_t)32 * 256 * 2;
    ushort* e1wt = (ushort*)p; p += (size_t)256 * 32 * 2;
    ushort* e2wt = (ushort*)p; p += (size_t)1024 * 256 * 2;
    ushort* q1wt = (ushort*)p; p += (size_t)256 * 1024 * 2;
    ushort* q2wt = (ushort*)p; p += (size_t)32 * 256 * 2;

    // 0. weight transpose + bf16 convert
    wt_cvt<<<dim3(8, 1),  256, 0, stream>>>(kw,  kwt,  256, 32);
    wt_cvt<<<dim3(1, 8),  256, 0, stream>>>(e1w, e1wt, 32, 256);
    wt_cvt<<<dim3(8, 32), 256, 0, stream>>>(e2w, e2wt, 256, 1024);
    wt_cvt<<<dim3(32, 8), 256, 0, stream>>>(q1w, q1wt, 1024, 256);
    wt_cvt<<<dim3(8, 1),  256, 0, stream>>>(q2w, q2wt, 256, 32);

    // 1. key = ee @ kw + kb  (M=262144, N=32, K=256), fp32 A staged->bf16, KEYMODE out
    mfma_gemm<128, 32, 32, 4, 1, false, false, false, true, true>
        <<<dim3(2048, 1), 256, 0, stream>>>(ee, 256, kwt, kb, nullptr, 0, key, 32, 256, 0);
    key_fixup<<<512, 32, 0, stream>>>(en, eemb, key);
    prep_kernel<<<512, 64, 0, stream>>>(en, su, sun, key, fs, EMBb);

    // 2. Z1 = relu(EMB @ e1w + e1b)   (M=32256, N=256, K=32)
    mfma_gemm<128, 128, 32, 2, 2, true, false, true, false, false>
        <<<dim3(252, 2), 256, 0, stream>>>(EMBb, 32, e1wt, e1b, nullptr, 0, Z1b, 256, 32, 0);
    ae_init<<<512, 256, 0, stream>>>(ar, AEb);
    // 3. AE[512..] = ar + Z1 @ e2w + e2b  (M=32256, N=1024, K=256)
    mfma_gemm<128, 128, 32, 2, 2, false, true, true, false, false>
        <<<dim3(252, 8), 256, 0, stream>>>(Z1b, 256, e2wt, e2b, ar, 1024, AEb, 1024, 256, 512);
    // 4. Y1 = relu(AE @ q1w + q1b)  (M=32768, N=256, K=1024)
    mfma_gemm<128, 128, 32, 2, 2, true, false, true, false, false>
        <<<dim3(256, 2), 256, 0, stream>>>(AEb, 1024, q1wt, q1b, nullptr, 0, Z1b, 256, 1024, 0);
    // 5. X = Y1 @ q2w + q2b  (M=32768, N=32, K=256), fp32 out
    mfma_gemm<128, 32, 32, 4, 1, false, false, false, false, false>
        <<<dim3(256, 1), 256, 0, stream>>>(Z1b, 256, q2wt, q2b, nullptr, 0, X, 32, 256, 0);

    // 6. LN-LSTM over 64 steps -> queries
    lstm_kernel<<<512, 128, 0, stream>>>(X, wih, whh, lnig, lnib, lnhg, lnhb, lncg, lncb, Q);

    // 7. logits + mask
    logits_kernel<<<dim3(512, 5), 128, 0, stream>>>(key, Q, fs, en, outp);
}

// Round 3
// 701.765 us; speedup vs baseline: 1.6143x; 1.0932x over previous
//
#include <hip/hip_runtime.h>
#include <cstdint>
#include <cstddef>

// Problem constants: BS=512, EN=512, SEQ=64, D_ENT=256, D_IN=1024, D_KEY=32, D_F=256, H=32

typedef short bf16x8 __attribute__((ext_vector_type(8)));
typedef float f32x4  __attribute__((ext_vector_type(4)));

__device__ __forceinline__ ushort f2bf(float f) {
    union { float f; unsigned u; } x; x.f = f;
    unsigned r = x.u + 0x7fffu + ((x.u >> 16) & 1u);   // round-to-nearest-even
    return (ushort)(r >> 16);
}

__device__ __forceinline__ void gld16(const void* g, void* l) {
    __builtin_amdgcn_global_load_lds(
        (const __attribute__((address_space(1))) void*)g,
        (__attribute__((address_space(3))) void*)l,
        16, 0, 0);
}

// ---------------------------------------------------------------------------
// bf16 MFMA GEMM: out = op(A[M,K] @ B[K,N] + bias [+ addvec]).
// B pre-transposed as BT[N,K] bf16. A bf16 (global_load_lds) or fp32 (cvt).
// KEYMODE remaps out row r=b*512+n into key layout [b][513][32].
// ---------------------------------------------------------------------------
template<int BM, int BN, int BK, int WR, int WC,
         bool RELU, bool ADDVEC, bool OUT_BF16, bool A_F32, bool KEYMODE>
__global__ __launch_bounds__(WR * WC * 64)
void mfma_gemm(const void* __restrict__ Av, int lda,
               const ushort* __restrict__ BT,
               const float* __restrict__ bias,
               const float* __restrict__ addvec, int ldadd,
               void* __restrict__ outv, int ldo,
               int K, int out_row_offset)
{
    constexpr int NT  = WR * WC * 64;
    constexpr int WM  = BM / WR, WN = BN / WC;
    constexpr int TMt = WM / 16, TNt = WN / 16;
    constexpr int KC  = BK / 8;          // 16B chunks per row
    constexpr int CHA = BM * KC, CHB = BN * KC;
    __shared__ __align__(16) ushort As[BM * BK];
    __shared__ __align__(16) ushort Bs[BN * BK];

    const int tid  = threadIdx.x;
    const int lane = tid & 63;
    const int w    = tid >> 6;
    const int wr   = w / WC, wc = w % WC;
    const int row0 = blockIdx.x * BM;
    const int n0   = blockIdx.y * BN;

    f32x4 acc[TMt][TNt];
#pragma unroll
    for (int i = 0; i < TMt; i++)
#pragma unroll
        for (int j = 0; j < TNt; j++)
#pragma unroll
            for (int r = 0; r < 4; r++) acc[i][j][r] = 0.f;

    const ushort* Ab = (const ushort*)Av;
    const float*  Af = (const float*)Av;

    for (int k0 = 0; k0 < K; k0 += BK) {
        if (A_F32) {
#pragma unroll
            for (int id = tid; id < CHA; id += NT) {
                int r = id / KC, kc = id % KC;
                const float* src = Af + (size_t)(row0 + r) * lda + k0 + kc * 8;
                float4 v0 = *(const float4*)(src);
                float4 v1 = *(const float4*)(src + 4);
                bf16x8 p;
                p[0] = (short)f2bf(v0.x); p[1] = (short)f2bf(v0.y);
                p[2] = (short)f2bf(v0.z); p[3] = (short)f2bf(v0.w);
                p[4] = (short)f2bf(v1.x); p[5] = (short)f2bf(v1.y);
                p[6] = (short)f2bf(v1.z); p[7] = (short)f2bf(v1.w);
                *(bf16x8*)(&As[id * 8]) = p;
            }
        } else {
#pragma unroll
            for (int id = tid; id < CHA; id += NT) {
                int r = id / KC, kc = id % KC;
                gld16(Ab + (size_t)(row0 + r) * lda + k0 + kc * 8, &As[id * 8]);
            }
        }
#pragma unroll
        for (int id = tid; id < CHB; id += NT) {
            int r = id / KC, kc = id % KC;
            gld16(BT + (size_t)(n0 + r) * K + k0 + kc * 8, &Bs[id * 8]);
        }
        __syncthreads();

        bf16x8 afr[TMt], bfr[TNt];
        const int krd = (lane >> 4) * 8;
        const int mrd = lane & 15;
#pragma unroll
        for (int tm = 0; tm < TMt; tm++)
            afr[tm] = *(bf16x8*)(&As[(wr * WM + tm * 16 + mrd) * BK + krd]);
#pragma unroll
        for (int tn = 0; tn < TNt; tn++)
            bfr[tn] = *(bf16x8*)(&Bs[(wc * WN + tn * 16 + mrd) * BK + krd]);
#pragma unroll
        for (int tm = 0; tm < TMt; tm++)
#pragma unroll
            for (int tn = 0; tn < TNt; tn++)
                acc[tm][tn] = __builtin_amdgcn_mfma_f32_16x16x32_bf16(
                    afr[tm], bfr[tn], acc[tm][tn], 0, 0, 0);
        __syncthreads();
    }

    // Epilogue. C layout: col = lane&15, row = (lane>>4)*4 + reg
    float*  outf = (float*)outv;
    ushort* outh = (ushort*)outv;
    const int cn = lane & 15;
    const int rb = (lane >> 4) * 4;
#pragma unroll
    for (int tm = 0; tm < TMt; tm++) {
#pragma unroll
        for (int r = 0; r < 4; r++) {
            int grow = row0 + wr * WM + tm * 16 + rb + r;
            int b_   = grow & 511;
#pragma unroll
            for (int tn = 0; tn < TNt; tn++) {
                int gcol = n0 + wc * WN + tn * 16 + cn;
                float v = acc[tm][tn][r] + bias[gcol];
                if (RELU)   v = fmaxf(v, 0.f);
                if (ADDVEC) v += addvec[(size_t)b_ * ldadd + gcol];
                size_t oidx;
                if (KEYMODE) oidx = ((size_t)(grow >> 9) * 513 + b_) * 32 + gcol;
                else         oidx = (size_t)(grow + out_row_offset) * ldo + gcol;
                if (OUT_BF16) outh[oidx] = f2bf(v);
                else          outf[oidx] = v;
            }
        }
    }
}

// ---------------------------------------------------------------------------
// misc_prep: ae_init (blocks 0..511) + all 5 weight transpose/cvt jobs
// ---------------------------------------------------------------------------
__global__ __launch_bounds__(256) void misc_prep(
    const float* __restrict__ kw,  const float* __restrict__ e1w,
    const float* __restrict__ e2w, const float* __restrict__ q1w,
    const float* __restrict__ q2w,
    ushort* __restrict__ kwt,  ushort* __restrict__ e1wt,
    ushort* __restrict__ e2wt, ushort* __restrict__ q1wt,
    ushort* __restrict__ q2wt,
    const float* __restrict__ ar, ushort* __restrict__ AEb)
{
    int bx = blockIdx.x;
    if (bx < 512) {
        int i = (bx * 256 + threadIdx.x) * 4;
        float4 v = *(const float4*)(ar + i);
        ushort4 o;
        o.x = f2bf(v.x); o.y = f2bf(v.y); o.z = f2bf(v.z); o.w = f2bf(v.w);
        *(ushort4*)(AEb + i) = o;
        return;
    }
    bx -= 512;
    const float* W; ushort* WT; int K, N, t0;
    if      (bx < 8)   { W = kw;  WT = kwt;  K = 256;  N = 32;   t0 = bx; }
    else if (bx < 16)  { W = e1w; WT = e1wt; K = 32;   N = 256;  t0 = bx - 8; }
    else if (bx < 272) { W = e2w; WT = e2wt; K = 256;  N = 1024; t0 = bx - 16; }
    else if (bx < 528) { W = q1w; WT = q1wt; K = 1024; N = 256;  t0 = bx - 272; }
    else               { W = q2w; WT = q2wt; K = 256;  N = 32;   t0 = bx - 528; }
    int nn = N >> 5;
    int kt = (t0 / nn) * 32, nt = (t0 % nn) * 32;
    __shared__ float t[32][33];
    int x = threadIdx.x & 31, y = threadIdx.x >> 5;
    for (int i = y; i < 32; i += 8) t[i][x] = W[(size_t)(kt + i) * N + nt + x];
    __syncthreads();
    for (int i = y; i < 32; i += 8) WT[(size_t)(nt + i) * K + kt + x] = f2bf(t[x][i]);
}

// ---------------------------------------------------------------------------
// prep: key fixup + first-occurrence fs[b][n] + end step T + pooled EMB (bf16)
// One wave (64 threads) per batch; selected key rows preloaded to LDS.
// ---------------------------------------------------------------------------
__global__ __launch_bounds__(64) void prep_kernel(
    const int* __restrict__ en_g, const int* __restrict__ su_g,
    const int* __restrict__ sun_g, float* __restrict__ key,
    const float* __restrict__ eemb,
    int* __restrict__ fs_g, ushort* __restrict__ EMB)
{
    int b = blockIdx.x;
    int tid = threadIdx.x;   // 64 = one wave
    __shared__ int fs_l[513];
    __shared__ int su_l[64];
    __shared__ float krows[64 * 32];
    for (int i = tid; i < 513; i += 64) fs_l[i] = 64;
    su_l[tid] = su_g[b * 64 + tid];
    int en = en_g[b];
    // key fixup (rows 512 and en are never read by the pooling below)
    if (tid < 32) key[((size_t)b * 513 + 512) * 32 + tid] = 0.f;
    else          key[((size_t)b * 513 + en) * 32 + (tid - 32)] = eemb[tid - 32];
    __syncthreads();
    atomicMin(&fs_l[su_l[tid]], tid);
    unsigned long long ball = __ballot(su_l[tid] == en);
    int T = ball ? (__ffsll(ball) - 1) : 64;
    __syncthreads();
    // preload the 64 selected-unit key rows (parallel, 2 rows per iteration)
    {
        int d = tid & 31;
#pragma unroll 4
        for (int i = 0; i < 32; i++) {
            int r = 2 * i + (tid >> 5);
            krows[r * 32 + d] = key[((size_t)b * 513 + su_l[r]) * 32 + d];
        }
    }
    for (int i = tid; i < 513; i += 64) fs_g[(size_t)b * 513 + i] = fs_l[i];
    __syncthreads();

    int sun = sun_g[b];
    float a = 0.f;
    int cnt = 0;
    for (int i = 0; i < 64; i++) {
        bool nw = (i < T) && (fs_l[su_l[i]] == i);
        if (nw) {
            cnt++;
            if (tid < 32) a += krows[i * 32 + tid];
        }
        float denom = (sun != 0 && cnt > 0) ? (float)cnt : 1.0f;
        if (tid < 32) EMB[((size_t)i * 512 + b) * 32 + tid] = f2bf(a / denom);
    }
}

// ---------------------------------------------------------------------------
// LN-LSTM: one WAVE per batch, no barriers in the step loop.
// Thread layout: lane holds gates (lane) and (lane+64); lanes j and j+32
// redundantly compute cell dim j = lane&31. X preloaded to LDS.
// ---------------------------------------------------------------------------
__device__ inline float sigm(float x) { return 1.0f / (1.0f + expf(-x)); }

__global__ __launch_bounds__(128) void lstm_kernel(
    const float* __restrict__ X, const float* __restrict__ wih_g,
    const float* __restrict__ whh_g,
    const float* __restrict__ lnig, const float* __restrict__ lnib,
    const float* __restrict__ lnhg, const float* __restrict__ lnhb,
    const float* __restrict__ lncg, const float* __restrict__ lncb,
    float* __restrict__ Q)
{
    const int wv = threadIdx.x >> 6;
    const int lane = threadIdx.x & 63;
    const int b = blockIdx.x * 2 + wv;
    __shared__ float xs[2][64 * 32];

    // prefetch X[s][b][:] for all 64 steps (2 steps per iteration, coalesced 128B)
    {
        int d = lane & 31;
#pragma unroll 8
        for (int i = 0; i < 32; i++) {
            int s = 2 * i + (lane >> 5);
            xs[wv][s * 32 + d] = X[((size_t)s * 512 + b) * 32 + d];
        }
    }
    // weights into registers: my two gate columns of w_ih / w_hh
    float w0[32], w1[32], u0[32], u1[32];
#pragma unroll
    for (int k = 0; k < 32; k++) {
        w0[k] = wih_g[k * 128 + lane];
        w1[k] = wih_g[k * 128 + lane + 64];
        u0[k] = whh_g[k * 128 + lane];
        u1[k] = whh_g[k * 128 + lane + 64];
    }
    const float gi0 = lnig[lane], gi1 = lnig[lane + 64];
    const float bi0 = lnib[lane], bi1 = lnib[lane + 64];
    const float gh0 = lnhg[lane], gh1 = lnhg[lane + 64];
    const float bh0 = lnhb[lane], bh1 = lnhb[lane + 64];
    const int j = lane & 31;
    const float gc = lncg[j], bc = lncb[j];
    float h = 0.f, c = 0.f;
    __syncthreads();   // xs visible within each wave

    const float* xrow = &xs[wv][0];
    for (int s = 0; s < 64; s++) {
        float ax0 = 0.f, ax1 = 0.f, ah0 = 0.f, ah1 = 0.f;
#pragma unroll
        for (int k = 0; k < 32; k++) {
            float xk = xrow[s * 32 + k];     // LDS broadcast
            float hk = __shfl(h, k);
            ax0 += xk * w0[k]; ax1 += xk * w1[k];
            ah0 += hk * u0[k]; ah1 += hk * u1[k];
        }
        // LN stats over the 128 gates (2 per lane)
        float r0 = ax0 + ax1, r1 = ax0 * ax0 + ax1 * ax1;
        float r2 = ah0 + ah1, r3 = ah0 * ah0 + ah1 * ah1;
#pragma unroll
        for (int m = 1; m <= 32; m <<= 1) {
            r0 += __shfl_xor(r0, m); r1 += __shfl_xor(r1, m);
            r2 += __shfl_xor(r2, m); r3 += __shfl_xor(r3, m);
        }
        float mx = r0 * (1.f / 128.f), vx = r1 * (1.f / 128.f) - mx * mx;
        float mh = r2 * (1.f / 128.f), vh = r3 * (1.f / 128.f) - mh * mh;
        float sx = rsqrtf(vx + 1e-5f), sh = rsqrtf(vh + 1e-5f);
        float g0 = (ax0 - mx) * sx * gi0 + bi0 + (ah0 - mh) * sh * gh0 + bh0;
        float g1 = (ax1 - mx) * sx * gi1 + bi1 + (ah1 - mh) * sh * gh1 + bh1;
        // gather my cell's 4 gates: i=g0@j, f=g0@(j+32), g=g1@j, o=g1@(j+32)
        float igv = __shfl(g0, j),      fgv = __shfl(g0, j + 32);
        float cgv = __shfl(g1, j),      ogv = __shfl(g1, j + 32);
        float cc = sigm(fgv) * c + sigm(igv) * tanhf(cgv);
        // LN over 32 cells (each duplicated twice across 64 lanes -> /64)
        float s0 = cc, s1 = cc * cc;
#pragma unroll
        for (int m = 1; m <= 32; m <<= 1) {
            s0 += __shfl_xor(s0, m); s1 += __shfl_xor(s1, m);
        }
        float mc = s0 * (1.f / 64.f), vc = s1 * (1.f / 64.f) - mc * mc;
        c = (cc - mc) * rsqrtf(vc + 1e-5f) * gc + bc;
        h = sigm(ogv) * tanhf(c);
        if (lane < 32) Q[((size_t)b * 64 + s) * 32 + lane] = h;
    }
}

// ---------------------------------------------------------------------------
// logits: out[b][s][n] = mask ? dot(Q[b][s], key[b][n]) : -1e9
// ---------------------------------------------------------------------------
__global__ __launch_bounds__(128) void logits_kernel(
    const float* __restrict__ key, const float* __restrict__ Q,
    const int* __restrict__ fs_g, const int* __restrict__ en_g,
    float* __restrict__ out)
{
    int b = blockIdx.x;
    int n0 = blockIdx.y * 128;
    int tid = threadIdx.x;
    __shared__ float Qs[64 * 32];
    __shared__ float Ks[128 * 33];
    for (int i = tid * 4; i < 2048; i += 512)
        *(float4*)(&Qs[i]) = *(const float4*)(Q + (size_t)b * 2048 + i);
    for (int i = tid; i < 4096; i += 128) {
        int r = i >> 5, d = i & 31;
        int n = n0 + r;
        Ks[r * 33 + d] = (n < 513) ? key[((size_t)b * 513 + n) * 32 + d] : 0.f;
    }
    __syncthreads();
    int n = n0 + tid;
    if (n < 513) {
        int en = en_g[b];
        int f = fs_g[(size_t)b * 513 + n];
        float kreg[32];
#pragma unroll
        for (int d = 0; d < 32; d++) kreg[d] = Ks[tid * 33 + d];
        for (int s = 0; s < 64; s++) {
            float a = 0.f;
#pragma unroll
            for (int d = 0; d < 32; d++) a += Qs[s * 32 + d] * kreg[d];
            bool m = (s == 0) ? (n < en) : ((n <= en) && (f >= s));
            out[((size_t)b * 64 + s) * 513 + n] = m ? a : -1e9f;
        }
    }
}

// ---------------------------------------------------------------------------
extern "C" void kernel_launch(void* const* d_in, const int* in_sizes, int n_in,
                              void* d_out, int out_size, void* d_ws, size_t ws_size,
                              hipStream_t stream)
{
    const float* ee   = (const float*)d_in[0];
    const float* ar   = (const float*)d_in[1];
    const int*   en   = (const int*)d_in[2];
    const int*   su   = (const int*)d_in[3];
    const int*   sun  = (const int*)d_in[4];
    const float* kw   = (const float*)d_in[5];
    const float* kb   = (const float*)d_in[6];
    const float* q1w  = (const float*)d_in[7];
    const float* q1b  = (const float*)d_in[8];
    const float* q2w  = (const float*)d_in[9];
    const float* q2b  = (const float*)d_in[10];
    const float* e1w  = (const float*)d_in[11];
    const float* e1b  = (const float*)d_in[12];
    const float* e2w  = (const float*)d_in[13];
    const float* e2b  = (const float*)d_in[14];
    const float* eemb = (const float*)d_in[15];
    const float* wih  = (const float*)d_in[16];
    const float* whh  = (const float*)d_in[17];
    const float* lnig = (const float*)d_in[18];
    const float* lnib = (const float*)d_in[19];
    const float* lnhg = (const float*)d_in[20];
    const float* lnhb = (const float*)d_in[21];
    const float* lncg = (const float*)d_in[22];
    const float* lncb = (const float*)d_in[23];
    float* outp = (float*)d_out;

    char* p = (char*)d_ws;
    float*  key  = (float*)p;  p += (size_t)512 * 513 * 32 * 4;   // 33.6 MB
    ushort* AEb  = (ushort*)p; p += (size_t)32768 * 1024 * 2;     // 67 MB
    ushort* Z1b  = (ushort*)p; p += (size_t)32768 * 256 * 2;      // 16.8 MB
    ushort* EMBb = (ushort*)p; p += (size_t)32768 * 32 * 2;       // 2 MB
    float*  X    = (float*)p;  p += (size_t)32768 * 32 * 4;       // 4 MB
    float*  Q    = (float*)p;  p += (size_t)32768 * 32 * 4;       // 4 MB
    int*    fs   = (int*)p;    p += (size_t)512 * 513 * 4;        // 1.05 MB
    ushort* kwt  = (ushort*)p; p += (size_t)32 * 256 * 2;
    ushort* e1wt = (ushort*)p; p += (size_t)256 * 32 * 2;
    ushort* e2wt = (ushort*)p; p += (size_t)1024 * 256 * 2;
    ushort* q1wt = (ushort*)p; p += (size_t)256 * 1024 * 2;
    ushort* q2wt = (ushort*)p; p += (size_t)32 * 256 * 2;

    // 0. ae_init + all weight transposes in one launch
    misc_prep<<<1048, 256, 0, stream>>>(kw, e1w, e2w, q1w, q2w,
                                        kwt, e1wt, e2wt, q1wt, q2wt, ar, AEb);

    // 1. key = ee @ kw + kb  (M=262144, N=32, K=256), fp32 A staged->bf16, KEYMODE out
    mfma_gemm<128, 32, 32, 4, 1, false, false, false, true, true>
        <<<dim3(2048, 1), 256, 0, stream>>>(ee, 256, kwt, kb, nullptr, 0, key, 32, 256, 0);
    // 2. key fixup + fs + pooled EMB
    prep_kernel<<<512, 64, 0, stream>>>(en, su, sun, key, eemb, fs, EMBb);

    // 3. Z1 = relu(EMB @ e1w + e1b)   (M=32256, N=256, K=32)
    mfma_gemm<128, 128, 32, 2, 2, true, false, true, false, false>
        <<<dim3(252, 2), 256, 0, stream>>>(EMBb, 32, e1wt, e1b, nullptr, 0, Z1b, 256, 32, 0);
    // 4. AE[512..] = ar + Z1 @ e2w + e2b  (M=32256, N=1024, K=256)
    mfma_gemm<128, 128, 32, 2, 2, false, true, true, false, false>
        <<<dim3(252, 8), 256, 0, stream>>>(Z1b, 256, e2wt, e2b, ar, 1024, AEb, 1024, 256, 512);
    // 5. Y1 = relu(AE @ q1w + q1b)  (M=32768, N=256, K=1024)
    mfma_gemm<128, 128, 32, 2, 2, true, false, true, false, false>
        <<<dim3(256, 2), 256, 0, stream>>>(AEb, 1024, q1wt, q1b, nullptr, 0, Z1b, 256, 1024, 0);
    // 6. X = Y1 @ q2w + q2b  (M=32768, N=32, K=256), fp32 out
    mfma_gemm<128, 32, 32, 4, 1, false, false, false, false, false>
        <<<dim3(256, 1), 256, 0, stream>>>(Z1b, 256, q2wt, q2b, nullptr, 0, X, 32, 256, 0);

    // 7. LN-LSTM over 64 steps -> queries (one wave per batch, barrier-free)
    lstm_kernel<<<256, 128, 0, stream>>>(X, wih, whh, lnig, lnib, lnhg, lnhb, lncg, lncb, Q);

    // 8. logits + mask
    logits_kernel<<<dim3(512, 5), 128, 0, stream>>>(key, Q, fs, en, outp);
}